// Round 1
// baseline (654.083 us; speedup 1.0000x reference)
//
#include <hip/hip_runtime.h>
#include <hip/hip_bf16.h>
#include <cstdint>

// Qwen3-VL-MoE text experts: permute -> grouped GEMM (gate_up) -> SwiGLU ->
// grouped GEMM (down) -> unpermute+combine.  bf16 MFMA path.

#define E_   32
#define H_   2048
#define D_   768
#define T_   4096
#define K_   8
#define M_   (T_ * K_)   // 32768 expanded rows
#define G_   (M_ / E_)   // 1024 rows per expert (balanced)
#define GU2  (2 * D_)    // 1536

typedef unsigned short u16;
typedef short bf16x8 __attribute__((ext_vector_type(8)));
typedef float f32x4 __attribute__((ext_vector_type(4)));
typedef unsigned short u16x2 __attribute__((ext_vector_type(2)));
typedef unsigned short u16x8 __attribute__((ext_vector_type(8)));

__device__ __forceinline__ u16 f2bf(float f) {          // RNE f32 -> bf16
  unsigned u = __float_as_uint(f);
  u += 0x7FFFu + ((u >> 16) & 1u);
  return (u16)(u >> 16);
}
__device__ __forceinline__ float bf2f(u16 v) {
  return __uint_as_float(((unsigned)v) << 16);
}

#define GLOAD16(g, l) __builtin_amdgcn_global_load_lds(                        \
    (const __attribute__((address_space(1))) void*)(g),                        \
    (__attribute__((address_space(3))) void*)(l), 16, 0, 0)

// ---------------------------------------------------------------- prep ------
__global__ __launch_bounds__(256) void cvt_hidden(const float* __restrict__ in,
                                                  u16* __restrict__ out) {
  const int i = blockIdx.x * 256 + threadIdx.x;       // float4 groups
  const float4 v = ((const float4*)in)[i];
  u16 o0 = f2bf(v.x), o1 = f2bf(v.y), o2 = f2bf(v.z), o3 = f2bf(v.w);
  u16x2 a; a.x = o0; a.y = o1;
  u16x2 b; b.x = o2; b.y = o3;
  *(u16x2*)&out[(size_t)i * 4]     = a;
  *(u16x2*)&out[(size_t)i * 4 + 2] = b;
}

// in: (B, R, C) f32  ->  out: (B, C, R) bf16.  R, C multiples of 64.
__global__ __launch_bounds__(256) void transpose_cvt(const float* __restrict__ in,
                                                     u16* __restrict__ out,
                                                     int R, int C) {
  __shared__ u16 tl[64][65];
  const int b = blockIdx.z;
  const int c0 = blockIdx.x * 64, r0 = blockIdx.y * 64;
  const float* ip = in + ((size_t)b * R + r0) * C + c0;
  const int lr = threadIdx.x >> 6;   // 0..3
  const int lc = threadIdx.x & 63;
#pragma unroll
  for (int p = 0; p < 16; ++p) {
    const int r = p * 4 + lr;
    tl[r][lc] = f2bf(ip[(size_t)r * C + lc]);
  }
  __syncthreads();
  u16* op = out + ((size_t)b * C + c0) * R + r0;
  const int wr = threadIdx.x >> 5;   // 0..7
  const int wi = threadIdx.x & 31;
#pragma unroll
  for (int p = 0; p < 8; ++p) {
    const int c = p * 8 + wr;
    u16x2 v; v.x = tl[2 * wi][c]; v.y = tl[2 * wi + 1][c];
    *(u16x2*)&op[(size_t)c * R + 2 * wi] = v;
  }
}

// ------------------------------------------------------------- routing -----
// Stable counting sort by expert id; balanced groups => base[e] = e*G_.
__global__ __launch_bounds__(256) void build_perm(const int* __restrict__ ridx,
                                                  int* __restrict__ perm_src) {
  const int e = blockIdx.x;
  const int lane = threadIdx.x & 63, wid = threadIdx.x >> 6;
  __shared__ int wcnt[4];
  __shared__ int running;
  if (threadIdx.x == 0) running = 0;
  __syncthreads();
  for (int base = 0; base < M_; base += 256) {
    const int i = base + threadIdx.x;
    const bool match = (ridx[i] == e);
    const unsigned long long mask = __ballot(match);
    if (lane == 0) wcnt[wid] = __popcll(mask);
    __syncthreads();
    int wpre = 0;
    for (int w0 = 0; w0 < wid; ++w0) wpre += wcnt[w0];
    const int rank = __popcll(mask & ((1ull << lane) - 1ull));
    if (match) perm_src[e * G_ + running + wpre + rank] = i;
    __syncthreads();
    if (threadIdx.x == 0) running += wcnt[0] + wcnt[1] + wcnt[2] + wcnt[3];
    __syncthreads();
  }
}

__global__ __launch_bounds__(256) void gather_probs(const int* __restrict__ ridx,
                                                    const float* __restrict__ rw,
                                                    float* __restrict__ probs) {
  const int i = blockIdx.x * 256 + threadIdx.x;   // i < M_
  const int t = i >> 3;
  probs[i] = rw[t * E_ + ridx[i]];
}

// --------------------------------------------------------------- GEMM1 -----
// C tile 128x128 (cols: 64 gate + 64 up), BK=64, 4 waves row-split (32x128).
// A: gathered hidden rows (bf16), B: gup_t (E,1536,H) k-contiguous bf16.
__global__ __launch_bounds__(256, 2) void gemm1_swiglu(
    const u16* __restrict__ hid, const u16* __restrict__ gup,
    const int* __restrict__ perm, u16* __restrict__ act) {
  __shared__ u16 Al[128 * 64];
  __shared__ u16 Bl[128 * 64];
  const int e = blockIdx.z, mb = blockIdx.y, nb = blockIdx.x;
  const int lane = threadIdx.x & 63, w = threadIdx.x >> 6;
  const int sr = lane >> 3, sc = lane & 7;

  const u16* pA[4]; const u16* pB[4];
#pragma unroll
  for (int i = 0; i < 4; ++i) {
    const int r = w * 32 + i * 8 + sr;
    const int token = perm[e * G_ + mb * 128 + r] >> 3;
    pA[i] = hid + (size_t)token * H_ + ((sc ^ (r & 7)) * 8);      // pre-swizzled src
    const int grow = (r < 64) ? (nb * 64 + r) : (D_ + nb * 64 + r - 64);
    pB[i] = gup + ((size_t)e * GU2 + grow) * H_ + ((sc ^ (r & 7)) * 8);
  }

  f32x4 acc[2][8];
#pragma unroll
  for (int m = 0; m < 2; ++m)
#pragma unroll
    for (int n = 0; n < 8; ++n) acc[m][n] = (f32x4){0.f, 0.f, 0.f, 0.f};

  for (int k0 = 0; k0 < H_; k0 += 64) {
#pragma unroll
    for (int i = 0; i < 4; ++i) {
      GLOAD16(pA[i] + k0, &Al[(w * 32 + i * 8) * 64]);
      GLOAD16(pB[i] + k0, &Bl[(w * 32 + i * 8) * 64]);
    }
    __syncthreads();
#pragma unroll
    for (int kk = 0; kk < 2; ++kk) {
      const int csel = (lane >> 4) + kk * 4;
      bf16x8 a[2], b[8];
#pragma unroll
      for (int m = 0; m < 2; ++m) {
        const int r = w * 32 + m * 16 + (lane & 15);
        a[m] = *(const bf16x8*)&Al[r * 64 + ((csel ^ (r & 7)) * 8)];
      }
#pragma unroll
      for (int n = 0; n < 8; ++n) {
        const int r = n * 16 + (lane & 15);
        b[n] = *(const bf16x8*)&Bl[r * 64 + ((csel ^ (r & 7)) * 8)];
      }
#pragma unroll
      for (int m = 0; m < 2; ++m)
#pragma unroll
        for (int n = 0; n < 8; ++n)
          acc[m][n] = __builtin_amdgcn_mfma_f32_16x16x32_bf16(a[m], b[n],
                                                              acc[m][n], 0, 0, 0);
    }
    __syncthreads();
  }

  const int lrow = (lane >> 4) * 4, lcol = lane & 15;
#pragma unroll
  for (int m = 0; m < 2; ++m)
#pragma unroll
    for (int n = 0; n < 4; ++n)
#pragma unroll
      for (int r = 0; r < 4; ++r) {
        const float g = acc[m][n][r];
        const float u = acc[m][n + 4][r];
        const float a_ = g / (1.f + __expf(-g)) * u;     // silu(g)*u
        const int row = mb * 128 + w * 32 + m * 16 + lrow + r;
        const int col = nb * 64 + n * 16 + lcol;
        act[((size_t)e * G_ + row) * D_ + col] = f2bf(a_);
      }
}

// --------------------------------------------------------------- GEMM2 -----
// C tile 128x128, BK=64, K=768; epilogue scatters rows to expanded order.
__global__ __launch_bounds__(256, 2) void gemm2_scatter(
    const u16* __restrict__ act, const u16* __restrict__ dwn,
    const int* __restrict__ perm, u16* __restrict__ expo) {
  __shared__ u16 Al[128 * 64];
  __shared__ u16 Bl[128 * 64];
  const int e = blockIdx.z, mb = blockIdx.y, nb = blockIdx.x;
  const int lane = threadIdx.x & 63, w = threadIdx.x >> 6;
  const int sr = lane >> 3, sc = lane & 7;

  const u16* pA[4]; const u16* pB[4];
#pragma unroll
  for (int i = 0; i < 4; ++i) {
    const int r = w * 32 + i * 8 + sr;
    pA[i] = act + ((size_t)e * G_ + mb * 128 + r) * D_ + ((sc ^ (r & 7)) * 8);
    pB[i] = dwn + ((size_t)e * H_ + nb * 128 + r) * D_ + ((sc ^ (r & 7)) * 8);
  }

  f32x4 acc[2][8];
#pragma unroll
  for (int m = 0; m < 2; ++m)
#pragma unroll
    for (int n = 0; n < 8; ++n) acc[m][n] = (f32x4){0.f, 0.f, 0.f, 0.f};

  for (int k0 = 0; k0 < D_; k0 += 64) {
#pragma unroll
    for (int i = 0; i < 4; ++i) {
      GLOAD16(pA[i] + k0, &Al[(w * 32 + i * 8) * 64]);
      GLOAD16(pB[i] + k0, &Bl[(w * 32 + i * 8) * 64]);
    }
    __syncthreads();
#pragma unroll
    for (int kk = 0; kk < 2; ++kk) {
      const int csel = (lane >> 4) + kk * 4;
      bf16x8 a[2], b[8];
#pragma unroll
      for (int m = 0; m < 2; ++m) {
        const int r = w * 32 + m * 16 + (lane & 15);
        a[m] = *(const bf16x8*)&Al[r * 64 + ((csel ^ (r & 7)) * 8)];
      }
#pragma unroll
      for (int n = 0; n < 8; ++n) {
        const int r = n * 16 + (lane & 15);
        b[n] = *(const bf16x8*)&Bl[r * 64 + ((csel ^ (r & 7)) * 8)];
      }
#pragma unroll
      for (int m = 0; m < 2; ++m)
#pragma unroll
        for (int n = 0; n < 8; ++n)
          acc[m][n] = __builtin_amdgcn_mfma_f32_16x16x32_bf16(a[m], b[n],
                                                              acc[m][n], 0, 0, 0);
    }
    __syncthreads();
  }

  const int lrow = (lane >> 4) * 4, lcol = lane & 15;
#pragma unroll
  for (int m = 0; m < 2; ++m)
#pragma unroll
    for (int r = 0; r < 4; ++r) {
      const int dst = e * G_ + mb * 128 + w * 32 + m * 16 + lrow + r;
      const int src = perm[dst];                 // expanded index t*K+k
      u16* orow = expo + (size_t)src * H_ + nb * 128;
#pragma unroll
      for (int n = 0; n < 8; ++n)
        orow[n * 16 + lcol] = f2bf(acc[m][n][r]);
    }
}

// ------------------------------------------------------------- combine -----
__global__ __launch_bounds__(256) void combine(const u16* __restrict__ expo,
                                               const float* __restrict__ probs,
                                               float* __restrict__ out) {
  const int t = blockIdx.x;
  const int h0 = threadIdx.x * 8;
  float r[8] = {0.f, 0.f, 0.f, 0.f, 0.f, 0.f, 0.f, 0.f};
#pragma unroll
  for (int k = 0; k < K_; ++k) {
    const float p = probs[t * K_ + k];
    const u16x8 v = *(const u16x8*)&expo[((size_t)(t * K_ + k)) * H_ + h0];
#pragma unroll
    for (int j = 0; j < 8; ++j) r[j] += p * bf2f(v[j]);
  }
  float4 o0 = {r[0], r[1], r[2], r[3]};
  float4 o1 = {r[4], r[5], r[6], r[7]};
  *(float4*)&out[(size_t)t * H_ + h0]     = o0;
  *(float4*)&out[(size_t)t * H_ + h0 + 4] = o1;
}

// -------------------------------------------------------------- launch -----
extern "C" void kernel_launch(void* const* d_in, const int* in_sizes, int n_in,
                              void* d_out, int out_size, void* d_ws, size_t ws_size,
                              hipStream_t stream) {
  const float* hidden = (const float*)d_in[0];   // (T, H) f32
  const float* rw     = (const float*)d_in[1];   // (T, E) f32
  const int*   ridx   = (const int*)d_in[2];     // (T, K) i32
  const float* gup_f  = (const float*)d_in[3];   // (E, H, 2D) f32
  const float* dwn_f  = (const float*)d_in[4];   // (E, D, H) f32
  float* out = (float*)d_out;                    // (T, H) f32

  char* ws = (char*)d_ws;
  size_t off = 0;
  auto alloc = [&](size_t bytes) -> void* {
    void* p = ws + off;
    off += (bytes + 255) & ~(size_t)255;
    return p;
  };
  u16*   hid_bf = (u16*)alloc((size_t)T_ * H_ * 2);        //  16.8 MB
  u16*   gup_t  = (u16*)alloc((size_t)E_ * GU2 * H_ * 2);  // 201.3 MB (E,1536,H)
  u16*   dwn_t  = (u16*)alloc((size_t)E_ * H_ * D_ * 2);   // 100.7 MB (E,H,D)
  u16*   act    = (u16*)alloc((size_t)M_ * D_ * 2);        //  50.3 MB
  u16*   expo   = (u16*)alloc((size_t)M_ * H_ * 2);        // 134.2 MB
  int*   perm   = (int*)alloc((size_t)M_ * 4);
  float* probs  = (float*)alloc((size_t)M_ * 4);
  if (off > ws_size) return;   // workspace too small -> clean fail

  cvt_hidden<<<(T_ * H_ / 4) / 256, 256, 0, stream>>>(hidden, hid_bf);
  transpose_cvt<<<dim3(GU2 / 64, H_ / 64, E_), 256, 0, stream>>>(gup_f, gup_t, H_, GU2);
  transpose_cvt<<<dim3(H_ / 64, D_ / 64, E_), 256, 0, stream>>>(dwn_f, dwn_t, D_, H_);
  build_perm<<<E_, 256, 0, stream>>>(ridx, perm);
  gather_probs<<<M_ / 256, 256, 0, stream>>>(ridx, rw, probs);
  gemm1_swiglu<<<dim3(D_ / 64, G_ / 128, E_), 256, 0, stream>>>(hid_bf, gup_t, perm, act);
  gemm2_scatter<<<dim3(H_ / 128, G_ / 128, E_), 256, 0, stream>>>(act, dwn_t, perm, expo);
  combine<<<T_, 256, 0, stream>>>(expo, probs, out);
}